// Round 12
// baseline (658.752 us; speedup 1.0000x reference)
//
#include <hip/hip_runtime.h>
#include <stdint.h>
#include <stddef.h>

#define S_LEN 2048
#define BATCH 2
#define NHEADS 32
#define NKV 8
#define HD 128
#define HIDDEN 4096
#define T_TOK (BATCH * S_LEN)
// fused QKV activation row: [0,4096)=Q heads, [4096,5120)=K, [5120,6144)=V
#define QKV_W 6144

typedef unsigned short u16;
typedef __attribute__((ext_vector_type(4))) float f32x4;
typedef __attribute__((ext_vector_type(16))) float f32x16;
typedef __attribute__((ext_vector_type(8))) short s16x8;
typedef __attribute__((ext_vector_type(4))) unsigned short u16x4;
typedef __attribute__((ext_vector_type(4))) unsigned int u32x4;

__device__ __forceinline__ u16 f2bf(float f) {
  unsigned int u = __builtin_bit_cast(unsigned int, f);
  unsigned int r = (u + 0x7FFFu + ((u >> 16) & 1u)) >> 16;
  return (u16)r;
}
__device__ __forceinline__ float bf2f(u16 h) {
  return __builtin_bit_cast(float, ((unsigned int)h) << 16);
}

__device__ __forceinline__ void gload16(const void* g, void* l) {
  __builtin_amdgcn_global_load_lds((__attribute__((address_space(1))) void*)g,
                                   (__attribute__((address_space(3))) void*)l,
                                   16, 0, 0);
}

__device__ __forceinline__ unsigned cvtpk(float a, float b) {
  unsigned r;
  asm("v_cvt_pk_bf16_f32 %0, %1, %2" : "=v"(r) : "v"(a), "v"(b));
  return r;
}
__device__ __forceinline__ void lohi_dup(unsigned W, unsigned& lo, unsigned& hi) {
  unsigned a = W, b = W;
  asm volatile("v_permlane32_swap_b32 %0, %1" : "+v"(a), "+v"(b));
  lo = a; hi = b;
}

// ---------------- convert f32 -> bf16 (8 elems / thread) ----------------
__global__ __launch_bounds__(256) void k_convert(const float* __restrict__ in,
                                                 u16* __restrict__ out, int n8) {
  int i = blockIdx.x * 256 + threadIdx.x;
  if (i >= n8) return;
  float4 a = ((const float4*)in)[i * 2];
  float4 b = ((const float4*)in)[i * 2 + 1];
  u16x4 lo = {f2bf(a.x), f2bf(a.y), f2bf(a.z), f2bf(a.w)};
  u16x4 hi = {f2bf(b.x), f2bf(b.y), f2bf(b.z), f2bf(b.w)};
  ((u16x4*)out)[i * 2] = lo;
  ((u16x4*)out)[i * 2 + 1] = hi;
}

// ------------- transpose-convert W [K][N] f32 -> Wt [N][K] bf16 ----------
__global__ __launch_bounds__(256) void k_transpose_w(const float* __restrict__ W,
                                                     u16* __restrict__ Wt, int K,
                                                     int N, int outRowOff,
                                                     int outStride) {
  __shared__ float tl[32][33];
  int k0 = blockIdx.x * 32, n0 = blockIdx.y * 32;
  int t = threadIdx.x;
  int r = t >> 3, c4 = (t & 7) * 4;
  float4 v = *(const float4*)&W[(size_t)(k0 + r) * N + n0 + c4];
  tl[r][c4] = v.x; tl[r][c4 + 1] = v.y; tl[r][c4 + 2] = v.z; tl[r][c4 + 3] = v.w;
  __syncthreads();
  u16x4 o = {f2bf(tl[c4][r]), f2bf(tl[c4 + 1][r]), f2bf(tl[c4 + 2][r]),
             f2bf(tl[c4 + 3][r])};
  *(u16x4*)&Wt[(size_t)(outRowOff + n0 + r) * outStride + k0 + c4] = o;
}

// ---------------- RoPE cos/sin table: tab[s][0:64]=cos, [64:128]=sin -----
__global__ __launch_bounds__(256) void k_rope_tab(const int* __restrict__ pos,
                                                  float* __restrict__ tab) {
  int i = blockIdx.x * 256 + threadIdx.x;  // S*64
  int s = i >> 6, l = i & 63;
  float p = (float)pos[s];
  float ang = p * expf(-(float)l * 0.14391156516342163f);
  tab[s * 128 + l] = cosf(ang);
  tab[s * 128 + 64 + l] = sinf(ang);
}

// ===== 128x128xBK64 4-wave GEMM, 2 blocks/CU cross-domain overlap ==========
// Rationale (R11 counters): 256^2 1-block/CU kernel was lockstep-alternating
// DS-read and MFMA windows (MfmaUtil 33%, 0 conflicts) + 1.5-round tail.
// This kernel: 64 KiB LDS -> 2 independent blocks/CU whose barrier domains
// drift -> one block's ds_reads overlap the other's MFMAs. Exact-round grids
// (1536 = 3x512, 1024 = 2x512). ONE __syncthreads per K-tile (drains lgkm:
// prev reads retired; drains vmcnt: buf^1 fully staged) -- no inline waitcnt
// counting, no same-window WAR (stage ALWAYS targets buf^1).
// Waves 2M x 2N, per-wave 64x64 (acc 4x4 f32x4 = 64 VGPR).
template <typename OutT>
__global__ __launch_bounds__(256, 2) void k_gemm128(const u16* __restrict__ A,
                                                    const u16* __restrict__ Bt,
                                                    OutT* __restrict__ C,
                                                    int N, int K) {
  __shared__ u16 As[2][8192];   // [buf][128 rows][64 k], xor-swizzled
  __shared__ u16 Bs[2][8192];
  int nbn = N >> 7;
  int nwg = gridDim.x;
  int orig = blockIdx.x;
  int q8 = nwg >> 3, r8 = nwg & 7;
  int xcd = orig & 7, sub = orig >> 3;
  int wgid = (xcd < r8 ? xcd * (q8 + 1) : r8 * (q8 + 1) + (xcd - r8) * q8) + sub;
  int bm = wgid / nbn, bn = wgid % nbn;
  int tid = threadIdx.x, wid = tid >> 6, lane = tid & 63;
  int wm = wid >> 1, wn = wid & 1;  // 2M x 2N waves; per-wave 64x64
  int g = lane >> 4, c = lane & 15;
  int l3 = lane >> 3, l7 = lane & 7;
  int swz = c & 7;
  int xunit = (l7 ^ l3) * 8;  // inverse-swizzled 16B unit for staging

  f32x4 acc[4][4];
#pragma unroll
  for (int m = 0; m < 4; m++)
#pragma unroll
    for (int n = 0; n < 4; n++) acc[m][n] = (f32x4){0.f, 0.f, 0.f, 0.f};

  const u16* aBase = A + (size_t)(bm * 128 + wid * 32 + l3) * K + xunit;
  const u16* bBase = Bt + (size_t)(bn * 128 + wid * 32 + l3) * K + xunit;

  auto stgA = [&](int buf, int j, size_t koff) {
    gload16(aBase + (size_t)(j * 8) * K + koff, &As[buf][(wid * 32 + j * 8) * 64]);
  };
  auto stgB = [&](int buf, int j, size_t koff) {
    gload16(bBase + (size_t)(j * 8) * K + koff, &Bs[buf][(wid * 32 + j * 8) * 64]);
  };

  int nt = K >> 6;
  // prologue: stage tile 0 -> buf0 (8 instrs/wave)
#pragma unroll
  for (int j = 0; j < 4; j++) { stgA(0, j, 0); stgB(0, j, 0); }
  __syncthreads();  // vmcnt(0): tile 0 landed

  for (int t = 0; t < nt; t++) {
    int cb = t & 1;
    const u16* Ab = &As[cb][0];
    const u16* Bb = &Bs[cb][0];
    bool s1 = (t + 1 < nt);
    size_t k1 = (size_t)(t + 1) << 6;

    // fragment reads (plain LDS loads; compiler emits fine-grained lgkmcnt)
    s16x8 af[4][2], bf[4][2];
#pragma unroll
    for (int mi = 0; mi < 4; mi++)
#pragma unroll
      for (int ks = 0; ks < 2; ks++)
        af[mi][ks] = *(const s16x8*)&Ab[(wm * 64 + mi * 16 + c) * 64 +
                                        (((ks * 4 + g) ^ swz) * 8)];
#pragma unroll
    for (int nj = 0; nj < 4; nj++)
#pragma unroll
      for (int ks = 0; ks < 2; ks++)
        bf[nj][ks] = *(const s16x8*)&Bb[(wn * 64 + nj * 16 + c) * 64 +
                                        (((ks * 4 + g) ^ swz) * 8)];
    // stage tile t+1 -> buf^1 (buf^1's last reads retired at the previous
    // __syncthreads -- never stage the consumed buffer)
    if (s1) {
#pragma unroll
      for (int j = 0; j < 4; j++) { stgA(cb ^ 1, j, k1); stgB(cb ^ 1, j, k1); }
    }
    __builtin_amdgcn_s_setprio(1);
#pragma unroll
    for (int mi = 0; mi < 4; mi++)
#pragma unroll
      for (int nj = 0; nj < 4; nj++)
#pragma unroll
        for (int ks = 0; ks < 2; ks++)
          acc[mi][nj] = __builtin_amdgcn_mfma_f32_16x16x32_bf16(
              af[mi][ks], bf[nj][ks], acc[mi][nj], 0, 0, 0);
    __builtin_amdgcn_s_setprio(0);
    __syncthreads();  // lgkm: reads retired; vmcnt: t+1 fully staged
  }

  // epilogue
#pragma unroll
  for (int m = 0; m < 4; m++)
#pragma unroll
    for (int n = 0; n < 4; n++) {
      size_t row = (size_t)bm * 128 + wm * 64 + m * 16 + g * 4;
      size_t col = (size_t)bn * 128 + wn * 64 + n * 16 + c;
#pragma unroll
      for (int r = 0; r < 4; r++) {
        float v = acc[m][n][r];
        if constexpr (sizeof(OutT) == 2)
          C[(row + r) * N + col] = (OutT)f2bf(v);
        else
          C[(row + r) * N + col] = (OutT)v;
      }
    }
}

// ------------- fused per-head RMSNorm + RoPE (in-place, bf16) ------------
__global__ __launch_bounds__(256) void k_rmsrope(u16* __restrict__ QK,
                                                 const float* __restrict__ w,
                                                 const float* __restrict__ tab,
                                                 int H, int rowStride) {
  int row = blockIdx.x * 4 + (threadIdx.x >> 6);
  int lane = threadIdx.x & 63;
  int t = row / H, h = row - t * H;
  int s = t & (S_LEN - 1);
  u16* p = QK + (size_t)t * rowStride + h * HD;
  float x1 = bf2f(p[lane]), x2 = bf2f(p[lane + 64]);
  float ss = x1 * x1 + x2 * x2;
#pragma unroll
  for (int o = 32; o >= 1; o >>= 1) ss += __shfl_xor(ss, o);
  float inv = rsqrtf(ss * (1.0f / 128.0f) + 1e-6f);
  float y1 = x1 * inv * w[lane], y2 = x2 * inv * w[lane + 64];
  float cs = tab[s * 128 + lane], sn = tab[s * 128 + 64 + lane];
  p[lane] = f2bf(y1 * cs - y2 * sn);
  p[lane + 64] = f2bf(y2 * cs + y1 * sn);
}

// ---- transpose V: QKV[t][5120 + kh*128 + d] -> Vt[bkh*128+d][s] ----
__global__ __launch_bounds__(256) void k_transpose_v(const u16* __restrict__ QKV,
                                                     u16* __restrict__ Vt) {
  __shared__ u16 tl[32][40];
  int bkh = blockIdx.x;
  int s0 = blockIdx.y * 32, d0 = blockIdx.z * 32;
  int b = bkh >> 3, kh = bkh & 7;
  int t = threadIdx.x, r = t >> 3, c4 = (t & 7) * 4;
  const u16* src =
      QKV + (size_t)(b * S_LEN + s0 + r) * QKV_W + 5120 + kh * HD + d0 + c4;
  u16x4 v = *(const u16x4*)src;
  tl[r][c4] = v[0]; tl[r][c4 + 1] = v[1]; tl[r][c4 + 2] = v[2]; tl[r][c4 + 3] = v[3];
  __syncthreads();
  u16x4 o = {tl[c4][r], tl[c4 + 1][r], tl[c4 + 2][r], tl[c4 + 3][r]};
  *(u16x4*)&Vt[(size_t)(bkh * HD + d0 + r) * S_LEN + s0 + c4] = o;
}

// --------------------------- causal GQA attention ------------------------
// R7-PROVEN structure (do not touch sync): 512 blocks, XCD-grouped (xcd owns
// 2 (b,kh) groups -> KV L2-resident); each block = one (b,h) processing
// q-tile PAIR {p, 15-p} -> uniform 34 chunks. K,V both double-buffered in
// 64 KiB LDS; ONE __syncthreads per chunk (stages next chunk into buf^1).
// Log2-domain softmax, T12 repack, T13 defer-max, T5 setprio.
__global__ __launch_bounds__(256) void k_attn(const u16* __restrict__ QKV,
                                              const u16* __restrict__ Vt,
                                              u16* __restrict__ Oact) {
  __shared__ u16 Ks[2][64 * 128];
  __shared__ u16 Vs[2][128 * 64];
  int bid = blockIdx.x;
  int xcd = bid & 7, slot = bid >> 3;
  int grp = xcd * 2 + (slot >> 5);  // 16 groups = b*8 + kh
  int b = grp >> 3, kh = grp & 7;
  int s32 = slot & 31;
  int pr = s32 >> 2;
  int h = kh * 4 + (s32 & 3);
  int w = threadIdx.x >> 6, lane = threadIdx.x & 63;
  int q31 = lane & 31, hh = lane >> 5;
  const float qscale = 0.12751740810f;  // 1/sqrt(128) * log2(e)

  const char* Kg = (const char*)(QKV + (size_t)b * S_LEN * QKV_W + 4096 + kh * HD);
  const char* Vg = (const char*)(Vt + (size_t)(b * 8 + kh) * HD * S_LEN);

#pragma unroll 1
  for (int half = 0; half < 2; half++) {
    __syncthreads();  // half-boundary safety: all prior LDS reads retired
    int qt = half ? 15 - pr : pr;
    int qw0 = qt * 128 + w * 32;

    // Q fragments (B operand: q = lane&31, d = dc*16 + hh*8 + e)
    s16x8 qf[8];
    const u16* Qp = QKV + (size_t)(b * S_LEN + qw0 + q31) * QKV_W + h * HD + hh * 8;
#pragma unroll
    for (int dc = 0; dc < 8; dc++) {
      s16x8 raw = *(const s16x8*)(Qp + dc * 16);
#pragma unroll
      for (int e = 0; e < 8; e++)
        qf[dc][e] = (short)f2bf(bf2f((u16)raw[e]) * qscale);
    }

    f32x16 o[4];
#pragma unroll
    for (int d = 0; d < 4; d++)
#pragma unroll
      for (int r = 0; r < 16; r++) o[d][r] = 0.f;
    float m = -3.0e38f, l = 0.f;

    int nch = 2 * qt + 2;

    // prologue: stage chunk 0 into buffer 0
    {
      char* KsB = (char*)Ks[0];
      char* VsB = (char*)Vs[0];
#pragma unroll
      for (int j = 0; j < 4; j++) {
        int ins = w * 4 + j;
        int row = ins * 4 + (lane >> 4);
        int bc = ((lane & 15) * 16) ^ ((row & 7) << 4);
        gload16(Kg + (size_t)row * 12288 + bc, KsB + ins * 1024);
      }
#pragma unroll
      for (int j = 0; j < 4; j++) {
        int ins = w * 4 + j;
        int row = ins * 8 + (lane >> 3);
        int bc = ((lane & 7) * 16) ^ ((row & 7) << 4);
        gload16(Vg + (size_t)row * 4096 + bc, VsB + ins * 1024);
      }
    }

    int cur = 0;
    for (int ch = 0; ch < nch; ch++) {
      int kb = ch * 64;
      __syncthreads();  // drains vmcnt (buf[cur] staged) + prev reads done
      if (ch + 1 < nch) {  // stage next chunk into buf[cur^1], overlapped
        char* KsB = (char*)Ks[cur ^ 1];
        char* VsB = (char*)Vs[cur ^ 1];
        int kb2 = kb + 64;
#pragma unroll
        for (int j = 0; j < 4; j++) {
          int ins = w * 4 + j;
          int row = ins * 4 + (lane >> 4);
          int bc = ((lane & 15) * 16) ^ ((row & 7) << 4);
          gload16(Kg + (size_t)(kb2 + row) * 12288 + bc, KsB + ins * 1024);
        }
#pragma unroll
        for (int j = 0; j < 4; j++) {
          int ins = w * 4 + j;
          int row = ins * 8 + (lane >> 3);
          int bc = ((lane & 7) * 16) ^ ((row & 7) << 4);
          gload16(Vg + (size_t)row * 4096 + (size_t)kb2 * 2 + bc, VsB + ins * 1024);
        }
      }
      if (kb <= qw0 + 31) {
        char* KsB = (char*)Ks[cur];
        char* VsB = (char*)Vs[cur];
        f32x16 sA, sB;
#pragma unroll
        for (int r = 0; r < 16; r++) { sA[r] = 0.f; sB[r] = 0.f; }
        int sw = (q31 & 7) << 4;
        __builtin_amdgcn_s_setprio(1);
#pragma unroll
        for (int dc = 0; dc < 8; dc++) {
          s16x8 kfA = *(const s16x8*)(KsB + q31 * 256 + ((dc * 32 + hh * 16) ^ sw));
          s16x8 kfB = *(const s16x8*)(KsB + (32 + q31) * 256 + ((dc * 32 + hh * 16) ^ sw));
          sA = __builtin_amdgcn_mfma_f32_32x32x16_bf16(kfA, qf[dc], sA, 0, 0, 0);
          sB = __builtin_amdgcn_mfma_f32_32x32x16_bf16(kfB, qf[dc], sB, 0, 0, 0);
        }
        __builtin_amdgcn_s_setprio(0);
        if (kb + 63 > qw0) {
          int qa = qw0 + q31;
#pragma unroll
          for (int r = 0; r < 16; r++) {
            int krow = (r & 3) + 8 * (r >> 2) + 4 * hh;
            if (kb + krow > qa) sA[r] = -1e30f;
            if (kb + 32 + krow > qa) sB[r] = -1e30f;
          }
        }
        float mx = -3.0e38f;
#pragma unroll
        for (int r = 0; r < 16; r++) mx = fmaxf(mx, fmaxf(sA[r], sB[r]));
        mx = fmaxf(mx, __shfl_xor(mx, 32));
        if (!__all(mx - m <= 11.5f)) {  // defer-max (T13, log2 units)
          float mnew = fmaxf(m, mx);
          float corr = __builtin_amdgcn_exp2f(m - mnew);
          l *= corr;
#pragma unroll
          for (int d = 0; d < 4; d++)
#pragma unroll
            for (int r = 0; r < 16; r++) o[d][r] *= corr;
          m = mnew;
        }
        float rs = 0.f;
#pragma unroll
        for (int r = 0; r < 16; r++) {
          sA[r] = __builtin_amdgcn_exp2f(sA[r] - m); rs += sA[r];
          sB[r] = __builtin_amdgcn_exp2f(sB[r] - m); rs += sB[r];
        }
        rs += __shfl_xor(rs, 32);
        l += rs;
#pragma unroll
        for (int st = 0; st < 2; st++) {
          unsigned Aw[8], Bw[8];
#pragma unroll
          for (int j = 0; j < 8; j++) {
            float p0 = st ? sB[2 * j] : sA[2 * j];
            float p1 = st ? sB[2 * j + 1] : sA[2 * j + 1];
            lohi_dup(cvtpk(p0, p1), Aw[j], Bw[j]);
          }
#pragma unroll
          for (int kc2 = 0; kc2 < 2; kc2++) {
            u32x4 wv;
            wv.x = hh ? Aw[kc2 * 4 + 2] : Aw[kc2 * 4 + 0];
            wv.y = hh ? Aw[kc2 * 4 + 3] : Aw[kc2 * 4 + 1];
            wv.z = hh ? Bw[kc2 * 4 + 2] : Bw[kc2 * 4 + 0];
            wv.w = hh ? Bw[kc2 * 4 + 3] : Bw[kc2 * 4 + 1];
            s16x8 pf = __builtin_bit_cast(s16x8, wv);
            int kc = st * 2 + kc2;
            __builtin_amdgcn_s_setprio(1);
#pragma unroll
            for (int d = 0; d < 4; d++) {
              int row = d * 32 + q31;
              int vsw = (row & 7) << 4;
              s16x8 vf = *(const s16x8*)(VsB + row * 128 + ((kc * 32 + hh * 16) ^ vsw));
              o[d] = __builtin_amdgcn_mfma_f32_32x32x16_bf16(vf, pf, o[d], 0, 0, 0);
            }
            __builtin_amdgcn_s_setprio(0);
          }
        }
      }
      cur ^= 1;
    }
    // epilogue: O^T C-layout -> Oact[token][h*128+d]
    float linv = 1.0f / l;
    u16* Op = Oact + (size_t)(b * S_LEN + qw0 + q31) * 4096 + h * HD;
#pragma unroll
    for (int d = 0; d < 4; d++)
#pragma unroll
      for (int g4 = 0; g4 < 4; g4++) {
        int d0 = d * 32 + 8 * g4 + 4 * hh;
        u16x4 w4 = {f2bf(o[d][4 * g4 + 0] * linv), f2bf(o[d][4 * g4 + 1] * linv),
                    f2bf(o[d][4 * g4 + 2] * linv), f2bf(o[d][4 * g4 + 3] * linv)};
        *(u16x4*)(Op + d0) = w4;
      }
  }
}

extern "C" void kernel_launch(void* const* d_in, const int* in_sizes, int n_in,
                              void* d_out, int out_size, void* d_ws,
                              size_t ws_size, hipStream_t stream) {
  (void)in_sizes; (void)n_in; (void)out_size; (void)ws_size;
  const float* X = (const float*)d_in[0];
  const int* pos = (const int*)d_in[1];
  const float* Wq = (const float*)d_in[2];
  const float* Wk = (const float*)d_in[3];
  const float* Wv = (const float*)d_in[4];
  const float* Wo = (const float*)d_in[5];
  const float* qw = (const float*)d_in[6];
  const float* kw = (const float*)d_in[7];
  float* out = (float*)d_out;
  char* ws = (char*)d_ws;

  const size_t MB = 1024ull * 1024ull;
  u16* Xb    = (u16*)(ws + 0 * MB);     // [4096][4096] bf16     32 MiB
  u16* WqkvT = (u16*)(ws + 32 * MB);    // [6144][4096] fused    48 MiB
  u16* WkvT  = (u16*)(ws + 64 * MB);    //   (rows 4096..6143 of WqkvT)
  u16* WoT   = (u16*)(ws + 80 * MB);    // [4096][4096]          32 MiB
  u16* QKV   = (u16*)(ws + 112 * MB);   // [4096][6144]          48 MiB
  u16* Vt    = (u16*)(ws + 160 * MB);   // [16*128][2048]         8 MiB
  u16* Oact  = (u16*)(ws + 168 * MB);   // [4096][4096]          32 MiB
  float* tab = (float*)(ws + 200 * MB); // [2048][128]            1 MiB

  k_convert<<<8192, 256, 0, stream>>>(X, Xb, (T_TOK * HIDDEN) / 8);
  k_transpose_w<<<dim3(128, 128), 256, 0, stream>>>(Wq, WqkvT, 4096, 4096, 0, 4096);
  k_transpose_w<<<dim3(128, 32), 256, 0, stream>>>(Wk, WkvT, 4096, 1024, 0, 4096);
  k_transpose_w<<<dim3(128, 32), 256, 0, stream>>>(Wv, WkvT, 4096, 1024, 1024, 4096);
  k_transpose_w<<<dim3(128, 128), 256, 0, stream>>>(Wo, WoT, 4096, 4096, 0, 4096);
  k_rope_tab<<<512, 256, 0, stream>>>(pos, tab);

  // fused QKV projection: [4096][4096] x [6144][4096]^T -> [4096][6144]
  k_gemm128<u16><<<32 * 48, 256, 0, stream>>>(Xb, WqkvT, QKV, QKV_W, 4096);

  k_rmsrope<<<(T_TOK * NHEADS) / 4, 256, 0, stream>>>(QKV, qw, tab, NHEADS, QKV_W);
  k_rmsrope<<<(T_TOK * NKV) / 4, 256, 0, stream>>>(QKV + 4096, kw, tab, NKV, QKV_W);

  k_transpose_v<<<dim3(16, 64, 4), 256, 0, stream>>>(QKV, Vt);

  k_attn<<<512, 256, 0, stream>>>(QKV, Vt, Oact);

  k_gemm128<float><<<32 * 32, 256, 0, stream>>>(Oact, WoT, out, 4096, 4096);
}

// Round 13
// 643.232 us; speedup vs baseline: 1.0241x; 1.0241x over previous
//
#include <hip/hip_runtime.h>
#include <stdint.h>
#include <stddef.h>

#define S_LEN 2048
#define BATCH 2
#define NHEADS 32
#define NKV 8
#define HD 128
#define HIDDEN 4096
#define T_TOK (BATCH * S_LEN)
// fused QKV activation row: [0,4096)=Q heads, [4096,5120)=K, [5120,6144)=V
#define QKV_W 6144

typedef unsigned short u16;
typedef __attribute__((ext_vector_type(4))) float f32x4;
typedef __attribute__((ext_vector_type(16))) float f32x16;
typedef __attribute__((ext_vector_type(8))) short s16x8;
typedef __attribute__((ext_vector_type(4))) unsigned short u16x4;
typedef __attribute__((ext_vector_type(4))) unsigned int u32x4;

__device__ __forceinline__ u16 f2bf(float f) {
  unsigned int u = __builtin_bit_cast(unsigned int, f);
  unsigned int r = (u + 0x7FFFu + ((u >> 16) & 1u)) >> 16;
  return (u16)r;
}
__device__ __forceinline__ float bf2f(u16 h) {
  return __builtin_bit_cast(float, ((unsigned int)h) << 16);
}

__device__ __forceinline__ void gload16(const void* g, void* l) {
  __builtin_amdgcn_global_load_lds((__attribute__((address_space(1))) void*)g,
                                   (__attribute__((address_space(3))) void*)l,
                                   16, 0, 0);
}

__device__ __forceinline__ unsigned cvtpk(float a, float b) {
  unsigned r;
  asm("v_cvt_pk_bf16_f32 %0, %1, %2" : "=v"(r) : "v"(a), "v"(b));
  return r;
}
__device__ __forceinline__ void lohi_dup(unsigned W, unsigned& lo, unsigned& hi) {
  unsigned a = W, b = W;
  asm volatile("v_permlane32_swap_b32 %0, %1" : "+v"(a), "+v"(b));
  lo = a; hi = b;
}

// ---------------- convert f32 -> bf16 (8 elems / thread) ----------------
__global__ __launch_bounds__(256) void k_convert(const float* __restrict__ in,
                                                 u16* __restrict__ out, int n8) {
  int i = blockIdx.x * 256 + threadIdx.x;
  if (i >= n8) return;
  float4 a = ((const float4*)in)[i * 2];
  float4 b = ((const float4*)in)[i * 2 + 1];
  u16x4 lo = {f2bf(a.x), f2bf(a.y), f2bf(a.z), f2bf(a.w)};
  u16x4 hi = {f2bf(b.x), f2bf(b.y), f2bf(b.z), f2bf(b.w)};
  ((u16x4*)out)[i * 2] = lo;
  ((u16x4*)out)[i * 2 + 1] = hi;
}

// ------------- transpose-convert W [K][N] f32 -> Wt [N][K] bf16 ----------
__global__ __launch_bounds__(256) void k_transpose_w(const float* __restrict__ W,
                                                     u16* __restrict__ Wt, int K,
                                                     int N, int outRowOff,
                                                     int outStride) {
  __shared__ float tl[32][33];
  int k0 = blockIdx.x * 32, n0 = blockIdx.y * 32;
  int t = threadIdx.x;
  int r = t >> 3, c4 = (t & 7) * 4;
  float4 v = *(const float4*)&W[(size_t)(k0 + r) * N + n0 + c4];
  tl[r][c4] = v.x; tl[r][c4 + 1] = v.y; tl[r][c4 + 2] = v.z; tl[r][c4 + 3] = v.w;
  __syncthreads();
  u16x4 o = {f2bf(tl[c4][r]), f2bf(tl[c4 + 1][r]), f2bf(tl[c4 + 2][r]),
             f2bf(tl[c4 + 3][r])};
  *(u16x4*)&Wt[(size_t)(outRowOff + n0 + r) * outStride + k0 + c4] = o;
}

// ---------------- RoPE cos/sin table: tab[s][0:64]=cos, [64:128]=sin -----
__global__ __launch_bounds__(256) void k_rope_tab(const int* __restrict__ pos,
                                                  float* __restrict__ tab) {
  int i = blockIdx.x * 256 + threadIdx.x;  // S*64
  int s = i >> 6, l = i & 63;
  float p = (float)pos[s];
  float ang = p * expf(-(float)l * 0.14391156516342163f);
  tab[s * 128 + l] = cosf(ang);
  tab[s * 128 + 64 + l] = sinf(ang);
}

// ===== 256x256xBK64 8-wave 8-PHASE GEMM (m201 template port) ==============
// 1 block/CU (128 KiB LDS, ~220 VGPR). 2 K-tiles/iter: tile 2j -> buf0
// (phases 0-3), 2j+1 -> buf1 (phases 4-7). Wave (wm,wn) owns 128x64 C.
// Phase = {ds-read quadrant frags, stage 1 half-tile, s_barrier, lgkm0,
// setprio(1), 16 MFMA, setprio(0), [vmcnt], s_barrier}.
// LIFETIME LEDGER (reads of buf0: A-h read p0(mh0)/p2(mh1); B halves read
// p0(nh0)/p1(nh1); buf1 same at p4-7):
//   stage p0,p1: (2j+1).A0,A1 -> buf1  (buf1 A last read prev p6; lgkm0+
//                trailing-barrier of prev p6 retired it)
//   stage p2,p3: (2j+2).B0,B1 -> buf0  (buf0 B last read p1)
//   stage p4,p5: (2j+2).A0,A1 -> buf0  (buf0 A last read p2)
//   stage p6,p7: (2j+3).B0,B1 -> buf1  (buf1 B last read p5)
// Every phase's ds_reads are consumed by its own MFMAs, so lgkmcnt(0) before
// the trailing barrier retires them before ANY wave can stage over them.
// VMCNT LEDGER (2 ops/half-tile/thread): end-p3 vmcnt(4): newest 4 = p2,p3
// stages -> everything older retired incl. (2j+1).A -> buf1 complete for
// p4-7. Final iter stages nothing at p2,p3 -> vmcnt(0) there (a counted wait
// would be a no-op over (2j+1).A itself -- the R8 bug class). end-p7
// vmcnt(4): newest 4 = p6,p7 -> (2j+2) complete for next iter's p0.
// Cross-wave safety: every vmcnt is followed by s_barrier before any
// dependent ds_read.
template <typename OutT>
__global__ __launch_bounds__(512, 2) void k_gemm8p(const u16* __restrict__ A,
                                                   const u16* __restrict__ Bt,
                                                   OutT* __restrict__ C,
                                                   int N, int K) {
  __shared__ u16 As[2][16384];  // [buf][256 rows][64 k], xor-swizzled rows
  __shared__ u16 Bs[2][16384];
  int nbn = N >> 8;
  int nwg = gridDim.x;
  int orig = blockIdx.x;
  int q8 = nwg >> 3, r8 = nwg & 7;
  int xcd = orig & 7, sub = orig >> 3;
  int wgid = (xcd < r8 ? xcd * (q8 + 1) : r8 * (q8 + 1) + (xcd - r8) * q8) + sub;
  int bm = wgid / nbn, bn = wgid % nbn;
  int tid = threadIdx.x, wid = tid >> 6, lane = tid & 63;
  int wm = wid >> 2, wn = wid & 3;  // 2M x 4N waves; wave tile 128x64
  int g = lane >> 4, c = lane & 15;
  int l3 = lane >> 3, l7 = lane & 7;
  int swz = c & 7;
  int xunit = (l7 ^ l3) * 8;  // inverse-swizzled 16B unit for staging

  f32x4 acc[8][4];
#pragma unroll
  for (int m = 0; m < 8; m++)
#pragma unroll
    for (int n = 0; n < 4; n++) acc[m][n] = (f32x4){0.f, 0.f, 0.f, 0.f};

  const u16* aBase = A + (size_t)(bm * 256 + wid * 16 + l3) * K + xunit;
  const u16* bBase = Bt + (size_t)(bn * 256 + wid * 16 + l3) * K + xunit;

  // stage one 128-row half-tile: 2 gload16 per thread (16 instrs per block)
  auto stgA = [&](int buf, int h, size_t koff) {
    gload16(aBase + (size_t)(h * 128) * K + koff,
            &As[buf][(h * 128 + wid * 16) * 64]);
    gload16(aBase + (size_t)(h * 128 + 8) * K + koff,
            &As[buf][(h * 128 + wid * 16 + 8) * 64]);
  };
  auto stgB = [&](int buf, int h, size_t koff) {
    gload16(bBase + (size_t)(h * 128) * K + koff,
            &Bs[buf][(h * 128 + wid * 16) * 64]);
    gload16(bBase + (size_t)(h * 128 + 8) * K + koff,
            &Bs[buf][(h * 128 + wid * 16 + 8) * 64]);
  };

  s16x8 af[4][2], bf0[2][2], bf1[2][2];
  auto rdA = [&](int buf, int mh) {
#pragma unroll
    for (int mi = 0; mi < 4; mi++)
#pragma unroll
      for (int ks = 0; ks < 2; ks++)
        af[mi][ks] = *(const s16x8*)&As[buf][(wm * 128 + mh * 64 + mi * 16 + c) * 64 +
                                            (((ks * 4 + g) ^ swz) * 8)];
  };
  auto rdB = [&](int buf, int nh, s16x8 (&bf)[2][2]) {
#pragma unroll
    for (int nj = 0; nj < 2; nj++)
#pragma unroll
      for (int ks = 0; ks < 2; ks++)
        bf[nj][ks] = *(const s16x8*)&Bs[buf][(wn * 64 + nh * 32 + nj * 16 + c) * 64 +
                                            (((ks * 4 + g) ^ swz) * 8)];
  };
  auto quad = [&](int mh, int nh, s16x8 (&bf)[2][2]) {
    __builtin_amdgcn_s_setprio(1);
#pragma unroll
    for (int mi = 0; mi < 4; mi++)
#pragma unroll
      for (int nj = 0; nj < 2; nj++)
#pragma unroll
        for (int ks = 0; ks < 2; ks++)
          acc[mh * 4 + mi][nh * 2 + nj] = __builtin_amdgcn_mfma_f32_16x16x32_bf16(
              af[mi][ks], bf[nj][ks], acc[mh * 4 + mi][nh * 2 + nj], 0, 0, 0);
    __builtin_amdgcn_s_setprio(0);
  };
#define BAR() __builtin_amdgcn_s_barrier()
#define LGKM0() asm volatile("s_waitcnt lgkmcnt(0)" ::: "memory")
#define VM(n) asm volatile("s_waitcnt vmcnt(" #n ")" ::: "memory")

  int nt2 = K >> 7;  // iterations; 2 K-tiles each (K=4096 -> 32)
  // prologue: t0 -> buf0 (B0,B1,A0,A1), t1.B -> buf1. 12 ops; vmcnt(4)
  // leaves only t1.B outstanding -> t0 complete.
  stgB(0, 0, 0); stgB(0, 1, 0);
  stgA(0, 0, 0); stgA(0, 1, 0);
  stgB(1, 0, 64); stgB(1, 1, 64);
  VM(4);
  BAR();

  for (int j = 0; j < nt2; j++) {
    size_t k1 = (size_t)(2 * j + 1) << 6;
    size_t k2 = (size_t)(2 * j + 2) << 6;
    size_t k3 = (size_t)(2 * j + 3) << 6;
    bool st = (j + 1 < nt2);  // stage tiles 2j+2, 2j+3?
    // ---- P0: tile 2j (buf0) Q(mh0,nh0); stage (2j+1).A0 -> buf1 ----
    rdA(0, 0); rdB(0, 0, bf0);
    stgA(1, 0, k1);
    BAR(); LGKM0();
    quad(0, 0, bf0);
    BAR();
    // ---- P1: Q(mh0,nh1); stage (2j+1).A1 -> buf1 ----
    rdB(0, 1, bf1);
    stgA(1, 1, k1);
    BAR(); LGKM0();
    quad(0, 1, bf1);
    BAR();
    // ---- P2: Q(mh1,nh0); stage (2j+2).B0 -> buf0 ----
    rdA(0, 1);
    if (st) stgB(0, 0, k2);
    BAR(); LGKM0();
    quad(1, 0, bf0);
    BAR();
    // ---- P3: Q(mh1,nh1); stage (2j+2).B1 -> buf0; WAIT(tile 2j+1) ----
    if (st) stgB(0, 1, k2);
    BAR(); LGKM0();
    quad(1, 1, bf1);
    if (st) { VM(4); } else { VM(0); }
    BAR();
    // ---- P4: tile 2j+1 (buf1) Q(mh0,nh0); stage (2j+2).A0 -> buf0 ----
    rdA(1, 0); rdB(1, 0, bf0);
    if (st) stgA(0, 0, k2);
    BAR(); LGKM0();
    quad(0, 0, bf0);
    BAR();
    // ---- P5: Q(mh0,nh1); stage (2j+2).A1 -> buf0 ----
    rdB(1, 1, bf1);
    if (st) stgA(0, 1, k2);
    BAR(); LGKM0();
    quad(0, 1, bf1);
    BAR();
    // ---- P6: Q(mh1,nh0); stage (2j+3).B0 -> buf1 ----
    rdA(1, 1);
    if (st) stgB(1, 0, k3);
    BAR(); LGKM0();
    quad(1, 0, bf0);
    BAR();
    // ---- P7: Q(mh1,nh1); stage (2j+3).B1 -> buf1; WAIT(tile 2j+2) ----
    if (st) stgB(1, 1, k3);
    BAR(); LGKM0();
    quad(1, 1, bf1);
    if (st) { VM(4); }
    BAR();
  }
#undef BAR
#undef LGKM0
#undef VM

  // epilogue
#pragma unroll
  for (int m = 0; m < 8; m++)
#pragma unroll
    for (int n = 0; n < 4; n++) {
      size_t row = (size_t)bm * 256 + wm * 128 + m * 16 + g * 4;
      size_t col = (size_t)bn * 256 + wn * 64 + n * 16 + c;
#pragma unroll
      for (int r = 0; r < 4; r++) {
        float v = acc[m][n][r];
        if constexpr (sizeof(OutT) == 2)
          C[(row + r) * N + col] = (OutT)f2bf(v);
        else
          C[(row + r) * N + col] = (OutT)v;
      }
    }
}

// ------------- fused per-head RMSNorm + RoPE (in-place, bf16) ------------
__global__ __launch_bounds__(256) void k_rmsrope(u16* __restrict__ QK,
                                                 const float* __restrict__ w,
                                                 const float* __restrict__ tab,
                                                 int H, int rowStride) {
  int row = blockIdx.x * 4 + (threadIdx.x >> 6);
  int lane = threadIdx.x & 63;
  int t = row / H, h = row - t * H;
  int s = t & (S_LEN - 1);
  u16* p = QK + (size_t)t * rowStride + h * HD;
  float x1 = bf2f(p[lane]), x2 = bf2f(p[lane + 64]);
  float ss = x1 * x1 + x2 * x2;
#pragma unroll
  for (int o = 32; o >= 1; o >>= 1) ss += __shfl_xor(ss, o);
  float inv = rsqrtf(ss * (1.0f / 128.0f) + 1e-6f);
  float y1 = x1 * inv * w[lane], y2 = x2 * inv * w[lane + 64];
  float cs = tab[s * 128 + lane], sn = tab[s * 128 + 64 + lane];
  p[lane] = f2bf(y1 * cs - y2 * sn);
  p[lane + 64] = f2bf(y2 * cs + y1 * sn);
}

// ---- transpose V: QKV[t][5120 + kh*128 + d] -> Vt[bkh*128+d][s] ----
__global__ __launch_bounds__(256) void k_transpose_v(const u16* __restrict__ QKV,
                                                     u16* __restrict__ Vt) {
  __shared__ u16 tl[32][40];
  int bkh = blockIdx.x;
  int s0 = blockIdx.y * 32, d0 = blockIdx.z * 32;
  int b = bkh >> 3, kh = bkh & 7;
  int t = threadIdx.x, r = t >> 3, c4 = (t & 7) * 4;
  const u16* src =
      QKV + (size_t)(b * S_LEN + s0 + r) * QKV_W + 5120 + kh * HD + d0 + c4;
  u16x4 v = *(const u16x4*)src;
  tl[r][c4] = v[0]; tl[r][c4 + 1] = v[1]; tl[r][c4 + 2] = v[2]; tl[r][c4 + 3] = v[3];
  __syncthreads();
  u16x4 o = {tl[c4][r], tl[c4 + 1][r], tl[c4 + 2][r], tl[c4 + 3][r]};
  *(u16x4*)&Vt[(size_t)(bkh * HD + d0 + r) * S_LEN + s0 + c4] = o;
}

// --------------------------- causal GQA attention ------------------------
// R7/R11-PROVEN structure (do not touch sync): 512 blocks, XCD-grouped;
// each block = one (b,h) processing q-tile PAIR {p, 15-p}; K,V double-
// buffered in 64 KiB LDS; ONE __syncthreads per chunk. Log2-domain softmax,
// T12 repack, T13 defer-max, T5 setprio.
__global__ __launch_bounds__(256) void k_attn(const u16* __restrict__ QKV,
                                              const u16* __restrict__ Vt,
                                              u16* __restrict__ Oact) {
  __shared__ u16 Ks[2][64 * 128];
  __shared__ u16 Vs[2][128 * 64];
  int bid = blockIdx.x;
  int xcd = bid & 7, slot = bid >> 3;
  int grp = xcd * 2 + (slot >> 5);  // 16 groups = b*8 + kh
  int b = grp >> 3, kh = grp & 7;
  int s32 = slot & 31;
  int pr = s32 >> 2;
  int h = kh * 4 + (s32 & 3);
  int w = threadIdx.x >> 6, lane = threadIdx.x & 63;
  int q31 = lane & 31, hh = lane >> 5;
  const float qscale = 0.12751740810f;  // 1/sqrt(128) * log2(e)

  const char* Kg = (const char*)(QKV + (size_t)b * S_LEN * QKV_W + 4096 + kh * HD);
  const char* Vg = (const char*)(Vt + (size_t)(b * 8 + kh) * HD * S_LEN);

#pragma unroll 1
  for (int half = 0; half < 2; half++) {
    __syncthreads();  // half-boundary safety: all prior LDS reads retired
    int qt = half ? 15 - pr : pr;
    int qw0 = qt * 128 + w * 32;

    s16x8 qf[8];
    const u16* Qp = QKV + (size_t)(b * S_LEN + qw0 + q31) * QKV_W + h * HD + hh * 8;
#pragma unroll
    for (int dc = 0; dc < 8; dc++) {
      s16x8 raw = *(const s16x8*)(Qp + dc * 16);
#pragma unroll
      for (int e = 0; e < 8; e++)
        qf[dc][e] = (short)f2bf(bf2f((u16)raw[e]) * qscale);
    }

    f32x16 o[4];
#pragma unroll
    for (int d = 0; d < 4; d++)
#pragma unroll
      for (int r = 0; r < 16; r++) o[d][r] = 0.f;
    float m = -3.0e38f, l = 0.f;

    int nch = 2 * qt + 2;

    {
      char* KsB = (char*)Ks[0];
      char* VsB = (char*)Vs[0];
#pragma unroll
      for (int j = 0; j < 4; j++) {
        int ins = w * 4 + j;
        int row = ins * 4 + (lane >> 4);
        int bc = ((lane & 15) * 16) ^ ((row & 7) << 4);
        gload16(Kg + (size_t)row * 12288 + bc, KsB + ins * 1024);
      }
#pragma unroll
      for (int j = 0; j < 4; j++) {
        int ins = w * 4 + j;
        int row = ins * 8 + (lane >> 3);
        int bc = ((lane & 7) * 16) ^ ((row & 7) << 4);
        gload16(Vg + (size_t)row * 4096 + bc, VsB + ins * 1024);
      }
    }

    int cur = 0;
    for (int ch = 0; ch < nch; ch++) {
      int kb = ch * 64;
      __syncthreads();
      if (ch + 1 < nch) {
        char* KsB = (char*)Ks[cur ^ 1];
        char* VsB = (char*)Vs[cur ^ 1];
        int kb2 = kb + 64;
#pragma unroll
        for (int j = 0; j < 4; j++) {
          int ins = w * 4 + j;
          int row = ins * 4 + (lane >> 4);
          int bc = ((lane & 15) * 16) ^ ((row & 7) << 4);
          gload16(Kg + (size_t)(kb2 + row) * 12288 + bc, KsB + ins * 1024);
        }
#pragma unroll
        for (int j = 0; j < 4; j++) {
          int ins = w * 4 + j;
          int row = ins * 8 + (lane >> 3);
          int bc = ((lane & 7) * 16) ^ ((row & 7) << 4);
          gload16(Vg + (size_t)row * 4096 + (size_t)kb2 * 2 + bc, VsB + ins * 1024);
        }
      }
      if (kb <= qw0 + 31) {
        char* KsB = (char*)Ks[cur];
        char* VsB = (char*)Vs[cur];
        f32x16 sA, sB;
#pragma unroll
        for (int r = 0; r < 16; r++) { sA[r] = 0.f; sB[r] = 0.f; }
        int sw = (q31 & 7) << 4;
        __builtin_amdgcn_s_setprio(1);
#pragma unroll
        for (int dc = 0; dc < 8; dc++) {
          s16x8 kfA = *(const s16x8*)(KsB + q31 * 256 + ((dc * 32 + hh * 16) ^ sw));
          s16x8 kfB = *(const s16x8*)(KsB + (32 + q31) * 256 + ((dc * 32 + hh * 16) ^ sw));
          sA = __builtin_amdgcn_mfma_f32_32x32x16_bf16(kfA, qf[dc], sA, 0, 0, 0);
          sB = __builtin_amdgcn_mfma_f32_32x32x16_bf16(kfB, qf[dc], sB, 0, 0, 0);
        }
        __builtin_amdgcn_s_setprio(0);
        if (kb + 63 > qw0) {
          int qa = qw0 + q31;
#pragma unroll
          for (int r = 0; r < 16; r++) {
            int krow = (r & 3) + 8 * (r >> 2) + 4 * hh;
            if (kb + krow > qa) sA[r] = -1e30f;
            if (kb + 32 + krow > qa) sB[r] = -1e30f;
          }
        }
        float mx = -3.0e38f;
#pragma unroll
        for (int r = 0; r < 16; r++) mx = fmaxf(mx, fmaxf(sA[r], sB[r]));
        mx = fmaxf(mx, __shfl_xor(mx, 32));
        if (!__all(mx - m <= 11.5f)) {
          float mnew = fmaxf(m, mx);
          float corr = __builtin_amdgcn_exp2f(m - mnew);
          l *= corr;
#pragma unroll
          for (int d = 0; d < 4; d++)
#pragma unroll
            for (int r = 0; r < 16; r++) o[d][r] *= corr;
          m = mnew;
        }
        float rs = 0.f;
#pragma unroll
        for (int r = 0; r < 16; r++) {
          sA[r] = __builtin_amdgcn_exp2f(sA[r] - m); rs += sA[r];
          sB[r] = __builtin_amdgcn_exp2f(sB[r] - m); rs += sB[r];
        }
        rs += __shfl_xor(rs, 32);
        l += rs;
#pragma unroll
        for (int st = 0; st < 2; st++) {
          unsigned Aw[8], Bw[8];
#pragma unroll
          for (int j = 0; j < 8; j++) {
            float p0 = st ? sB[2 * j] : sA[2 * j];
            float p1 = st ? sB[2 * j + 1] : sA[2 * j + 1];
            lohi_dup(cvtpk(p0, p1), Aw[j], Bw[j]);
          }
#pragma unroll
          for (int kc2 = 0; kc2 < 2; kc2++) {
            u32x4 wv;
            wv.x = hh ? Aw[kc2 * 4 + 2] : Aw[kc2 * 4 + 0];
            wv.y = hh ? Aw[kc2 * 4 + 3] : Aw[kc2 * 4 + 1];
            wv.z = hh ? Bw[kc2 * 4 + 2] : Bw[kc2 * 4 + 0];
            wv.w = hh ? Bw[kc2 * 4 + 3] : Bw[kc2 * 4 + 1];
            s16x8 pf = __builtin_bit_cast(s16x8, wv);
            int kc = st * 2 + kc2;
            __builtin_amdgcn_s_setprio(1);
#pragma unroll
            for (int d = 0; d < 4; d++) {
              int row = d * 32 + q31;
              int vsw = (row & 7) << 4;
              s16x8 vf = *(const s16x8*)(VsB + row * 128 + ((kc * 32 + hh * 16) ^ vsw));
              o[d] = __builtin_amdgcn_mfma_f32_32x32x16_bf16(vf, pf, o[d], 0, 0, 0);
            }
            __builtin_amdgcn_s_setprio(0);
          }
        }
      }
      cur ^= 1;
    }
    float linv = 1.0f / l;
    u16* Op = Oact + (size_t)(b * S_LEN + qw0 + q31) * 4096 + h * HD;
#pragma unroll
    for (int d = 0; d < 4; d++)
#pragma unroll
      for (int g4 = 0; g4 < 4; g4++) {
        int d0 = d * 32 + 8 * g4 + 4 * hh;
        u16x4 w4 = {f2bf(o[d][4 * g4 + 0] * linv), f2bf(o[d][4 * g4 + 1] * linv),
                    f2bf(o[d][4 * g4 + 2] * linv), f2bf(o[d][4 * g4 + 3] * linv)};
        *(u16x4*)(Op + d0) = w4;
      }
  }
}

extern "C" void kernel_launch(void* const* d_in, const int* in_sizes, int n_in,
                              void* d_out, int out_size, void* d_ws,
                              size_t ws_size, hipStream_t stream) {
  (void)in_sizes; (void)n_in; (void)out_size; (void)ws_size;
  const float* X = (const float*)d_in[0];
  const int* pos = (const int*)d_in[1];
  const float* Wq = (const float*)d_in[2];
  const float* Wk = (const float*)d_in[3];
  const float* Wv = (const float*)d_in[4];
  const float* Wo = (const float*)d_in[5];
  const float* qw = (const float*)d_in[6];
  const float* kw = (const float*)d_in[7];
  float* out = (float*)d_out;
  char* ws = (char*)d_ws;

  const size_t MB = 1024ull * 1024ull;
  u16* Xb    = (u16*)(ws + 0 * MB);     // [4096][4096] bf16     32 MiB
  u16* WqkvT = (u16*)(ws + 32 * MB);    // [6144][4096] fused    48 MiB
  u16* WkvT  = (u16*)(ws + 64 * MB);    //   (rows 4096..6143 of WqkvT)
  u16* WoT   = (u16*)(ws + 80 * MB);    // [4096][4096]          32 MiB
  u16* QKV   = (u16*)(ws + 112 * MB);   // [4096][6144]          48 MiB
  u16* Vt    = (u16*)(ws + 160 * MB);   // [16*128][2048]         8 MiB
  u16* Oact  = (u16*)(ws + 168 * MB);   // [4096][4096]          32 MiB
  float* tab = (float*)(ws + 200 * MB); // [2048][128]            1 MiB

  k_convert<<<8192, 256, 0, stream>>>(X, Xb, (T_TOK * HIDDEN) / 8);
  k_transpose_w<<<dim3(128, 128), 256, 0, stream>>>(Wq, WqkvT, 4096, 4096, 0, 4096);
  k_transpose_w<<<dim3(128, 32), 256, 0, stream>>>(Wk, WkvT, 4096, 1024, 0, 4096);
  k_transpose_w<<<dim3(128, 32), 256, 0, stream>>>(Wv, WkvT, 4096, 1024, 1024, 4096);
  k_transpose_w<<<dim3(128, 128), 256, 0, stream>>>(Wo, WoT, 4096, 4096, 0, 4096);
  k_rope_tab<<<512, 256, 0, stream>>>(pos, tab);

  // fused QKV projection: [4096][4096] x [6144][4096]^T -> [4096][6144]
  k_gemm8p<u16><<<16 * 24, 512, 0, stream>>>(Xb, WqkvT, QKV, QKV_W, 4096);

  k_rmsrope<<<(T_TOK * NHEADS) / 4, 256, 0, stream>>>(QKV, qw, tab, NHEADS, QKV_W);
  k_rmsrope<<<(T_TOK * NKV) / 4, 256, 0, stream>>>(QKV + 4096, kw, tab, NKV, QKV_W);

  k_transpose_v<<<dim3(16, 64, 4), 256, 0, stream>>>(QKV, Vt);

  k_attn<<<512, 256, 0, stream>>>(QKV, Vt, Oact);

  k_gemm8p<float><<<16 * 16, 512, 0, stream>>>(Oact, WoT, out, 4096, 4096);
}

// Round 14
// 630.832 us; speedup vs baseline: 1.0443x; 1.0197x over previous
//
#include <hip/hip_runtime.h>
#include <stdint.h>
#include <stddef.h>

#define S_LEN 2048
#define BATCH 2
#define NHEADS 32
#define NKV 8
#define HD 128
#define HIDDEN 4096
#define T_TOK (BATCH * S_LEN)
// fused QKV activation row: [0,4096)=Q heads, [4096,5120)=K, [5120,6144)=V
#define QKV_W 6144

typedef unsigned short u16;
typedef __attribute__((ext_vector_type(4))) float f32x4;
typedef __attribute__((ext_vector_type(16))) float f32x16;
typedef __attribute__((ext_vector_type(8))) short s16x8;
typedef __attribute__((ext_vector_type(4))) unsigned short u16x4;
typedef __attribute__((ext_vector_type(4))) unsigned int u32x4;

__device__ __forceinline__ u16 f2bf(float f) {
  unsigned int u = __builtin_bit_cast(unsigned int, f);
  unsigned int r = (u + 0x7FFFu + ((u >> 16) & 1u)) >> 16;
  return (u16)r;
}
__device__ __forceinline__ float bf2f(u16 h) {
  return __builtin_bit_cast(float, ((unsigned int)h) << 16);
}

__device__ __forceinline__ void gload16(const void* g, void* l) {
  __builtin_amdgcn_global_load_lds((__attribute__((address_space(1))) void*)g,
                                   (__attribute__((address_space(3))) void*)l,
                                   16, 0, 0);
}

__device__ __forceinline__ unsigned cvtpk(float a, float b) {
  unsigned r;
  asm("v_cvt_pk_bf16_f32 %0, %1, %2" : "=v"(r) : "v"(a), "v"(b));
  return r;
}
__device__ __forceinline__ void lohi_dup(unsigned W, unsigned& lo, unsigned& hi) {
  unsigned a = W, b = W;
  asm volatile("v_permlane32_swap_b32 %0, %1" : "+v"(a), "+v"(b));
  lo = a; hi = b;
}

// ---------------- convert f32 -> bf16 (8 elems / thread) ----------------
__global__ __launch_bounds__(256) void k_convert(const float* __restrict__ in,
                                                 u16* __restrict__ out, int n8) {
  int i = blockIdx.x * 256 + threadIdx.x;
  if (i >= n8) return;
  float4 a = ((const float4*)in)[i * 2];
  float4 b = ((const float4*)in)[i * 2 + 1];
  u16x4 lo = {f2bf(a.x), f2bf(a.y), f2bf(a.z), f2bf(a.w)};
  u16x4 hi = {f2bf(b.x), f2bf(b.y), f2bf(b.z), f2bf(b.w)};
  ((u16x4*)out)[i * 2] = lo;
  ((u16x4*)out)[i * 2 + 1] = hi;
}

// ------------- transpose-convert W [K][N] f32 -> Wt [N][K] bf16 ----------
__global__ __launch_bounds__(256) void k_transpose_w(const float* __restrict__ W,
                                                     u16* __restrict__ Wt, int K,
                                                     int N, int outRowOff,
                                                     int outStride) {
  __shared__ float tl[32][33];
  int k0 = blockIdx.x * 32, n0 = blockIdx.y * 32;
  int t = threadIdx.x;
  int r = t >> 3, c4 = (t & 7) * 4;
  float4 v = *(const float4*)&W[(size_t)(k0 + r) * N + n0 + c4];
  tl[r][c4] = v.x; tl[r][c4 + 1] = v.y; tl[r][c4 + 2] = v.z; tl[r][c4 + 3] = v.w;
  __syncthreads();
  u16x4 o = {f2bf(tl[c4][r]), f2bf(tl[c4 + 1][r]), f2bf(tl[c4 + 2][r]),
             f2bf(tl[c4 + 3][r])};
  *(u16x4*)&Wt[(size_t)(outRowOff + n0 + r) * outStride + k0 + c4] = o;
}

// ---------------- RoPE cos/sin table: tab[s][0:64]=cos, [64:128]=sin -----
__global__ __launch_bounds__(256) void k_rope_tab(const int* __restrict__ pos,
                                                  float* __restrict__ tab) {
  int i = blockIdx.x * 256 + threadIdx.x;  // S*64
  int s = i >> 6, l = i & 63;
  float p = (float)pos[s];
  float ang = p * expf(-(float)l * 0.14391156516342163f);
  tab[s * 128 + l] = cosf(ang);
  tab[s * 128 + 64 + l] = sinf(ang);
}

// ===== 256x256xBK64 8-wave 8-PHASE GEMM, ONE barrier per phase ============
// R13 post-mortem: two barriers/phase kept all 8 waves lockstep -> DS windows
// and MFMA windows strictly alternate (MfmaUtil 33%). This version drops the
// LEADING barrier: phase = {ds-read frags, stage half-tile, lgkm0+sched0,
// 16 MFMA, [vmcnt], s_barrier}. Waves skew WITHIN a phase -> one wave's
// ds_reads overlap another's MFMAs.
// SAFETY (exhaustive, all 8 phases):
//  (1) intra-phase: every stage target is disjoint from every read region of
//      the SAME phase (different array As/Bs or different buffer):
//      p0 stg As[1].h0 / rd As[0],Bs[0] | p1 stg As[1].h1 / rd Bs[0]
//      p2 stg Bs[0].h0 / rd As[0]       | p3 stg Bs[0].h1 / rd none
//      p4 stg As[0].h0 / rd As[1],Bs[1] | p5 stg As[0].h1 / rd Bs[1]
//      p6 stg Bs[1].h0 / rd As[1]       | p7 stg Bs[1].h1 / rd none
//  (2) cross-phase (stage p+1 vs read p, e.g. p2's Bs[0].h0 vs p1's nh1
//      reads): every wave's phase-p ds_reads retire at its lgkm0 BEFORE it
//      passes the trailing barrier of p; stages of p+1 issue after -> safe.
// VMCNT LEDGER (2 ops per half-tile stage): end-p3 VM(4) -> newest 4 = p2,p3
// stages; everything older (incl. (2j+1).A from p0,p1) retired -> buf1 ready
// for p4. FINAL iter: p2,p3 stage nothing -> VM(4) would no-op over the very
// loads we need (R8 bug class) -> VM(0) there. end-p7 VM(4) -> (2j+2) ready.
// Every VM is followed by s_barrier before any dependent ds_read.
template <typename OutT>
__global__ __launch_bounds__(512, 2) void k_gemm8p(const u16* __restrict__ A,
                                                   const u16* __restrict__ Bt,
                                                   OutT* __restrict__ C,
                                                   int N, int K) {
  __shared__ u16 As[2][16384];  // [buf][256 rows][64 k], xor-swizzled rows
  __shared__ u16 Bs[2][16384];
  int nbn = N >> 8;
  int nwg = gridDim.x;
  int orig = blockIdx.x;
  int q8 = nwg >> 3, r8 = nwg & 7;
  int xcd = orig & 7, sub = orig >> 3;
  int wgid = (xcd < r8 ? xcd * (q8 + 1) : r8 * (q8 + 1) + (xcd - r8) * q8) + sub;
  int bm = wgid / nbn, bn = wgid % nbn;
  int tid = threadIdx.x, wid = tid >> 6, lane = tid & 63;
  int wm = wid >> 2, wn = wid & 3;  // 2M x 4N waves; wave tile 128x64
  int g = lane >> 4, c = lane & 15;
  int l3 = lane >> 3, l7 = lane & 7;
  int swz = c & 7;
  int xunit = (l7 ^ l3) * 8;  // inverse-swizzled 16B unit for staging

  f32x4 acc[8][4];
#pragma unroll
  for (int m = 0; m < 8; m++)
#pragma unroll
    for (int n = 0; n < 4; n++) acc[m][n] = (f32x4){0.f, 0.f, 0.f, 0.f};

  const u16* aBase = A + (size_t)(bm * 256 + wid * 16 + l3) * K + xunit;
  const u16* bBase = Bt + (size_t)(bn * 256 + wid * 16 + l3) * K + xunit;

  // stage one 128-row half-tile: 2 gload16 per thread (16 instrs per block)
  auto stgA = [&](int buf, int h, size_t koff) {
    gload16(aBase + (size_t)(h * 128) * K + koff,
            &As[buf][(h * 128 + wid * 16) * 64]);
    gload16(aBase + (size_t)(h * 128 + 8) * K + koff,
            &As[buf][(h * 128 + wid * 16 + 8) * 64]);
  };
  auto stgB = [&](int buf, int h, size_t koff) {
    gload16(bBase + (size_t)(h * 128) * K + koff,
            &Bs[buf][(h * 128 + wid * 16) * 64]);
    gload16(bBase + (size_t)(h * 128 + 8) * K + koff,
            &Bs[buf][(h * 128 + wid * 16 + 8) * 64]);
  };

  s16x8 af[4][2], bf0[2][2], bf1[2][2];
  auto rdA = [&](int buf, int mh) {
#pragma unroll
    for (int mi = 0; mi < 4; mi++)
#pragma unroll
      for (int ks = 0; ks < 2; ks++)
        af[mi][ks] = *(const s16x8*)&As[buf][(wm * 128 + mh * 64 + mi * 16 + c) * 64 +
                                            (((ks * 4 + g) ^ swz) * 8)];
  };
  auto rdB = [&](int buf, int nh, s16x8 (&bf)[2][2]) {
#pragma unroll
    for (int nj = 0; nj < 2; nj++)
#pragma unroll
      for (int ks = 0; ks < 2; ks++)
        bf[nj][ks] = *(const s16x8*)&Bs[buf][(wn * 64 + nh * 32 + nj * 16 + c) * 64 +
                                            (((ks * 4 + g) ^ swz) * 8)];
  };
  auto quad = [&](int mh, int nh, s16x8 (&bf)[2][2]) {
    __builtin_amdgcn_s_setprio(1);
#pragma unroll
    for (int mi = 0; mi < 4; mi++)
#pragma unroll
      for (int nj = 0; nj < 2; nj++)
#pragma unroll
        for (int ks = 0; ks < 2; ks++)
          acc[mh * 4 + mi][nh * 2 + nj] = __builtin_amdgcn_mfma_f32_16x16x32_bf16(
              af[mi][ks], bf[nj][ks], acc[mh * 4 + mi][nh * 2 + nj], 0, 0, 0);
    __builtin_amdgcn_s_setprio(0);
  };
#define BAR() __builtin_amdgcn_s_barrier()
#define LGKM0()                                     \
  do {                                              \
    asm volatile("s_waitcnt lgkmcnt(0)" ::: "memory"); \
    __builtin_amdgcn_sched_barrier(0);              \
  } while (0)
#define VM(n) asm volatile("s_waitcnt vmcnt(" #n ")" ::: "memory")

  int nt2 = K >> 7;  // iterations; 2 K-tiles each (K=4096 -> 32)
  // prologue: t0 -> buf0 (B0,B1,A0,A1), t1.B -> buf1. 12 ops; vmcnt(4)
  // leaves only t1.B outstanding -> t0 complete.
  stgB(0, 0, 0); stgB(0, 1, 0);
  stgA(0, 0, 0); stgA(0, 1, 0);
  stgB(1, 0, 64); stgB(1, 1, 64);
  VM(4);
  BAR();

  for (int j = 0; j < nt2; j++) {
    size_t k1 = (size_t)(2 * j + 1) << 6;
    size_t k2 = (size_t)(2 * j + 2) << 6;
    size_t k3 = (size_t)(2 * j + 3) << 6;
    bool st = (j + 1 < nt2);  // stage tiles 2j+2, 2j+3?
    // ---- P0: tile 2j (buf0) Q(mh0,nh0); stage (2j+1).A0 -> buf1 ----
    rdA(0, 0); rdB(0, 0, bf0);
    stgA(1, 0, k1);
    LGKM0();
    quad(0, 0, bf0);
    BAR();
    // ---- P1: Q(mh0,nh1); stage (2j+1).A1 -> buf1 ----
    rdB(0, 1, bf1);
    stgA(1, 1, k1);
    LGKM0();
    quad(0, 1, bf1);
    BAR();
    // ---- P2: Q(mh1,nh0); stage (2j+2).B0 -> buf0 ----
    rdA(0, 1);
    if (st) stgB(0, 0, k2);
    LGKM0();
    quad(1, 0, bf0);
    BAR();
    // ---- P3: Q(mh1,nh1); stage (2j+2).B1 -> buf0; WAIT(tile 2j+1) ----
    if (st) stgB(0, 1, k2);
    LGKM0();
    quad(1, 1, bf1);
    if (st) { VM(4); } else { VM(0); }
    BAR();
    // ---- P4: tile 2j+1 (buf1) Q(mh0,nh0); stage (2j+2).A0 -> buf0 ----
    rdA(1, 0); rdB(1, 0, bf0);
    if (st) stgA(0, 0, k2);
    LGKM0();
    quad(0, 0, bf0);
    BAR();
    // ---- P5: Q(mh0,nh1); stage (2j+2).A1 -> buf0 ----
    rdB(1, 1, bf1);
    if (st) stgA(0, 1, k2);
    LGKM0();
    quad(0, 1, bf1);
    BAR();
    // ---- P6: Q(mh1,nh0); stage (2j+3).B0 -> buf1 ----
    rdA(1, 1);
    if (st) stgB(1, 0, k3);
    LGKM0();
    quad(1, 0, bf0);
    BAR();
    // ---- P7: Q(mh1,nh1); stage (2j+3).B1 -> buf1; WAIT(tile 2j+2) ----
    if (st) stgB(1, 1, k3);
    LGKM0();
    quad(1, 1, bf1);
    if (st) { VM(4); }
    BAR();
  }
#undef BAR
#undef LGKM0
#undef VM

  // epilogue
#pragma unroll
  for (int m = 0; m < 8; m++)
#pragma unroll
    for (int n = 0; n < 4; n++) {
      size_t row = (size_t)bm * 256 + wm * 128 + m * 16 + g * 4;
      size_t col = (size_t)bn * 256 + wn * 64 + n * 16 + c;
#pragma unroll
      for (int r = 0; r < 4; r++) {
        float v = acc[m][n][r];
        if constexpr (sizeof(OutT) == 2)
          C[(row + r) * N + col] = (OutT)f2bf(v);
        else
          C[(row + r) * N + col] = (OutT)v;
      }
    }
}

// ------------- fused per-head RMSNorm + RoPE (in-place, bf16) ------------
__global__ __launch_bounds__(256) void k_rmsrope(u16* __restrict__ QK,
                                                 const float* __restrict__ w,
                                                 const float* __restrict__ tab,
                                                 int H, int rowStride) {
  int row = blockIdx.x * 4 + (threadIdx.x >> 6);
  int lane = threadIdx.x & 63;
  int t = row / H, h = row - t * H;
  int s = t & (S_LEN - 1);
  u16* p = QK + (size_t)t * rowStride + h * HD;
  float x1 = bf2f(p[lane]), x2 = bf2f(p[lane + 64]);
  float ss = x1 * x1 + x2 * x2;
#pragma unroll
  for (int o = 32; o >= 1; o >>= 1) ss += __shfl_xor(ss, o);
  float inv = rsqrtf(ss * (1.0f / 128.0f) + 1e-6f);
  float y1 = x1 * inv * w[lane], y2 = x2 * inv * w[lane + 64];
  float cs = tab[s * 128 + lane], sn = tab[s * 128 + 64 + lane];
  p[lane] = f2bf(y1 * cs - y2 * sn);
  p[lane + 64] = f2bf(y2 * cs + y1 * sn);
}

// ---- transpose V: QKV[t][5120 + kh*128 + d] -> Vt[bkh*128+d][s] ----
__global__ __launch_bounds__(256) void k_transpose_v(const u16* __restrict__ QKV,
                                                     u16* __restrict__ Vt) {
  __shared__ u16 tl[32][40];
  int bkh = blockIdx.x;
  int s0 = blockIdx.y * 32, d0 = blockIdx.z * 32;
  int b = bkh >> 3, kh = bkh & 7;
  int t = threadIdx.x, r = t >> 3, c4 = (t & 7) * 4;
  const u16* src =
      QKV + (size_t)(b * S_LEN + s0 + r) * QKV_W + 5120 + kh * HD + d0 + c4;
  u16x4 v = *(const u16x4*)src;
  tl[r][c4] = v[0]; tl[r][c4 + 1] = v[1]; tl[r][c4 + 2] = v[2]; tl[r][c4 + 3] = v[3];
  __syncthreads();
  u16x4 o = {tl[c4][r], tl[c4 + 1][r], tl[c4 + 2][r], tl[c4 + 3][r]};
  *(u16x4*)&Vt[(size_t)(bkh * HD + d0 + r) * S_LEN + s0 + c4] = o;
}

// --------------------------- causal GQA attention ------------------------
// R7/R11-PROVEN structure (do not touch sync): 512 blocks, XCD-grouped;
// each block = one (b,h) processing q-tile PAIR {p, 15-p}; K,V double-
// buffered in 64 KiB LDS; ONE __syncthreads per chunk. Log2-domain softmax,
// T12 repack, T13 defer-max, T5 setprio.
__global__ __launch_bounds__(256) void k_attn(const u16* __restrict__ QKV,
                                              const u16* __restrict__ Vt,
                                              u16* __restrict__ Oact) {
  __shared__ u16 Ks[2][64 * 128];
  __shared__ u16 Vs[2][128 * 64];
  int bid = blockIdx.x;
  int xcd = bid & 7, slot = bid >> 3;
  int grp = xcd * 2 + (slot >> 5);  // 16 groups = b*8 + kh
  int b = grp >> 3, kh = grp & 7;
  int s32 = slot & 31;
  int pr = s32 >> 2;
  int h = kh * 4 + (s32 & 3);
  int w = threadIdx.x >> 6, lane = threadIdx.x & 63;
  int q31 = lane & 31, hh = lane >> 5;
  const float qscale = 0.12751740810f;  // 1/sqrt(128) * log2(e)

  const char* Kg = (const char*)(QKV + (size_t)b * S_LEN * QKV_W + 4096 + kh * HD);
  const char* Vg = (const char*)(Vt + (size_t)(b * 8 + kh) * HD * S_LEN);

#pragma unroll 1
  for (int half = 0; half < 2; half++) {
    __syncthreads();  // half-boundary safety: all prior LDS reads retired
    int qt = half ? 15 - pr : pr;
    int qw0 = qt * 128 + w * 32;

    s16x8 qf[8];
    const u16* Qp = QKV + (size_t)(b * S_LEN + qw0 + q31) * QKV_W + h * HD + hh * 8;
#pragma unroll
    for (int dc = 0; dc < 8; dc++) {
      s16x8 raw = *(const s16x8*)(Qp + dc * 16);
#pragma unroll
      for (int e = 0; e < 8; e++)
        qf[dc][e] = (short)f2bf(bf2f((u16)raw[e]) * qscale);
    }

    f32x16 o[4];
#pragma unroll
    for (int d = 0; d < 4; d++)
#pragma unroll
      for (int r = 0; r < 16; r++) o[d][r] = 0.f;
    float m = -3.0e38f, l = 0.f;

    int nch = 2 * qt + 2;

    {
      char* KsB = (char*)Ks[0];
      char* VsB = (char*)Vs[0];
#pragma unroll
      for (int j = 0; j < 4; j++) {
        int ins = w * 4 + j;
        int row = ins * 4 + (lane >> 4);
        int bc = ((lane & 15) * 16) ^ ((row & 7) << 4);
        gload16(Kg + (size_t)row * 12288 + bc, KsB + ins * 1024);
      }
#pragma unroll
      for (int j = 0; j < 4; j++) {
        int ins = w * 4 + j;
        int row = ins * 8 + (lane >> 3);
        int bc = ((lane & 7) * 16) ^ ((row & 7) << 4);
        gload16(Vg + (size_t)row * 4096 + bc, VsB + ins * 1024);
      }
    }

    int cur = 0;
    for (int ch = 0; ch < nch; ch++) {
      int kb = ch * 64;
      __syncthreads();
      if (ch + 1 < nch) {
        char* KsB = (char*)Ks[cur ^ 1];
        char* VsB = (char*)Vs[cur ^ 1];
        int kb2 = kb + 64;
#pragma unroll
        for (int j = 0; j < 4; j++) {
          int ins = w * 4 + j;
          int row = ins * 4 + (lane >> 4);
          int bc = ((lane & 15) * 16) ^ ((row & 7) << 4);
          gload16(Kg + (size_t)(kb2 + row) * 12288 + bc, KsB + ins * 1024);
        }
#pragma unroll
        for (int j = 0; j < 4; j++) {
          int ins = w * 4 + j;
          int row = ins * 8 + (lane >> 3);
          int bc = ((lane & 7) * 16) ^ ((row & 7) << 4);
          gload16(Vg + (size_t)row * 4096 + (size_t)kb2 * 2 + bc, VsB + ins * 1024);
        }
      }
      if (kb <= qw0 + 31) {
        char* KsB = (char*)Ks[cur];
        char* VsB = (char*)Vs[cur];
        f32x16 sA, sB;
#pragma unroll
        for (int r = 0; r < 16; r++) { sA[r] = 0.f; sB[r] = 0.f; }
        int sw = (q31 & 7) << 4;
        __builtin_amdgcn_s_setprio(1);
#pragma unroll
        for (int dc = 0; dc < 8; dc++) {
          s16x8 kfA = *(const s16x8*)(KsB + q31 * 256 + ((dc * 32 + hh * 16) ^ sw));
          s16x8 kfB = *(const s16x8*)(KsB + (32 + q31) * 256 + ((dc * 32 + hh * 16) ^ sw));
          sA = __builtin_amdgcn_mfma_f32_32x32x16_bf16(kfA, qf[dc], sA, 0, 0, 0);
          sB = __builtin_amdgcn_mfma_f32_32x32x16_bf16(kfB, qf[dc], sB, 0, 0, 0);
        }
        __builtin_amdgcn_s_setprio(0);
        if (kb + 63 > qw0) {
          int qa = qw0 + q31;
#pragma unroll
          for (int r = 0; r < 16; r++) {
            int krow = (r & 3) + 8 * (r >> 2) + 4 * hh;
            if (kb + krow > qa) sA[r] = -1e30f;
            if (kb + 32 + krow > qa) sB[r] = -1e30f;
          }
        }
        float mx = -3.0e38f;
#pragma unroll
        for (int r = 0; r < 16; r++) mx = fmaxf(mx, fmaxf(sA[r], sB[r]));
        mx = fmaxf(mx, __shfl_xor(mx, 32));
        if (!__all(mx - m <= 11.5f)) {
          float mnew = fmaxf(m, mx);
          float corr = __builtin_amdgcn_exp2f(m - mnew);
          l *= corr;
#pragma unroll
          for (int d = 0; d < 4; d++)
#pragma unroll
            for (int r = 0; r < 16; r++) o[d][r] *= corr;
          m = mnew;
        }
        float rs = 0.f;
#pragma unroll
        for (int r = 0; r < 16; r++) {
          sA[r] = __builtin_amdgcn_exp2f(sA[r] - m); rs += sA[r];
          sB[r] = __builtin_amdgcn_exp2f(sB[r] - m); rs += sB[r];
        }
        rs += __shfl_xor(rs, 32);
        l += rs;
#pragma unroll
        for (int st = 0; st < 2; st++) {
          unsigned Aw[8], Bw[8];
#pragma unroll
          for (int j = 0; j < 8; j++) {
            float p0 = st ? sB[2 * j] : sA[2 * j];
            float p1 = st ? sB[2 * j + 1] : sA[2 * j + 1];
            lohi_dup(cvtpk(p0, p1), Aw[j], Bw[j]);
          }
#pragma unroll
          for (int kc2 = 0; kc2 < 2; kc2++) {
            u32x4 wv;
            wv.x = hh ? Aw[kc2 * 4 + 2] : Aw[kc2 * 4 + 0];
            wv.y = hh ? Aw[kc2 * 4 + 3] : Aw[kc2 * 4 + 1];
            wv.z = hh ? Bw[kc2 * 4 + 2] : Bw[kc2 * 4 + 0];
            wv.w = hh ? Bw[kc2 * 4 + 3] : Bw[kc2 * 4 + 1];
            s16x8 pf = __builtin_bit_cast(s16x8, wv);
            int kc = st * 2 + kc2;
            __builtin_amdgcn_s_setprio(1);
#pragma unroll
            for (int d = 0; d < 4; d++) {
              int row = d * 32 + q31;
              int vsw = (row & 7) << 4;
              s16x8 vf = *(const s16x8*)(VsB + row * 128 + ((kc * 32 + hh * 16) ^ vsw));
              o[d] = __builtin_amdgcn_mfma_f32_32x32x16_bf16(vf, pf, o[d], 0, 0, 0);
            }
            __builtin_amdgcn_s_setprio(0);
          }
        }
      }
      cur ^= 1;
    }
    float linv = 1.0f / l;
    u16* Op = Oact + (size_t)(b * S_LEN + qw0 + q31) * 4096 + h * HD;
#pragma unroll
    for (int d = 0; d < 4; d++)
#pragma unroll
      for (int g4 = 0; g4 < 4; g4++) {
        int d0 = d * 32 + 8 * g4 + 4 * hh;
        u16x4 w4 = {f2bf(o[d][4 * g4 + 0] * linv), f2bf(o[d][4 * g4 + 1] * linv),
                    f2bf(o[d][4 * g4 + 2] * linv), f2bf(o[d][4 * g4 + 3] * linv)};
        *(u16x4*)(Op + d0) = w4;
      }
  }
}

extern "C" void kernel_launch(void* const* d_in, const int* in_sizes, int n_in,
                              void* d_out, int out_size, void* d_ws,
                              size_t ws_size, hipStream_t stream) {
  (void)in_sizes; (void)n_in; (void)out_size; (void)ws_size;
  const float* X = (const float*)d_in[0];
  const int* pos = (const int*)d_in[1];
  const float* Wq = (const float*)d_in[2];
  const float* Wk = (const float*)d_in[3];
  const float* Wv = (const float*)d_in[4];
  const float* Wo = (const float*)d_in[5];
  const float* qw = (const float*)d_in[6];
  const float* kw = (const float*)d_in[7];
  float* out = (float*)d_out;
  char* ws = (char*)d_ws;

  const size_t MB = 1024ull * 1024ull;
  u16* Xb    = (u16*)(ws + 0 * MB);     // [4096][4096] bf16     32 MiB
  u16* WqkvT = (u16*)(ws + 32 * MB);    // [6144][4096] fused    48 MiB
  u16* WkvT  = (u16*)(ws + 64 * MB);    //   (rows 4096..6143 of WqkvT)
  u16* WoT   = (u16*)(ws + 80 * MB);    // [4096][4096]          32 MiB
  u16* QKV   = (u16*)(ws + 112 * MB);   // [4096][6144]          48 MiB
  u16* Vt    = (u16*)(ws + 160 * MB);   // [16*128][2048]         8 MiB
  u16* Oact  = (u16*)(ws + 168 * MB);   // [4096][4096]          32 MiB
  float* tab = (float*)(ws + 200 * MB); // [2048][128]            1 MiB

  k_convert<<<8192, 256, 0, stream>>>(X, Xb, (T_TOK * HIDDEN) / 8);
  k_transpose_w<<<dim3(128, 128), 256, 0, stream>>>(Wq, WqkvT, 4096, 4096, 0, 4096);
  k_transpose_w<<<dim3(128, 32), 256, 0, stream>>>(Wk, WkvT, 4096, 1024, 0, 4096);
  k_transpose_w<<<dim3(128, 32), 256, 0, stream>>>(Wv, WkvT, 4096, 1024, 1024, 4096);
  k_transpose_w<<<dim3(128, 128), 256, 0, stream>>>(Wo, WoT, 4096, 4096, 0, 4096);
  k_rope_tab<<<512, 256, 0, stream>>>(pos, tab);

  // fused QKV projection: [4096][4096] x [6144][4096]^T -> [4096][6144]
  k_gemm8p<u16><<<16 * 24, 512, 0, stream>>>(Xb, WqkvT, QKV, QKV_W, 4096);

  k_rmsrope<<<(T_TOK * NHEADS) / 4, 256, 0, stream>>>(QKV, qw, tab, NHEADS, QKV_W);
  k_rmsrope<<<(T_TOK * NKV) / 4, 256, 0, stream>>>(QKV + 4096, kw, tab, NKV, QKV_W);

  k_transpose_v<<<dim3(16, 64, 4), 256, 0, stream>>>(QKV, Vt);

  k_attn<<<512, 256, 0, stream>>>(QKV, Vt, Oact);

  k_gemm8p<float><<<16 * 16, 512, 0, stream>>>(Oact, WoT, out, 4096, 4096);
}